// Round 1
// 1175.300 us; speedup vs baseline: 1.1233x; 1.1233x over previous
//
#include <hip/hip_runtime.h>
#include <hip/hip_bf16.h>

typedef __attribute__((ext_vector_type(8))) short short8;
typedef __attribute__((ext_vector_type(4))) short short4v;
typedef __attribute__((ext_vector_type(4))) float floatx4;

#define BM 256
#define BN 128
#define BK 32
#define CAP 256      // max tokens per expert (mean 128, sigma ~11 -> safe)
#define NEXP 32
#define NTOK 2048
#define DDIM 1024
#define HDIM 4096
#define HSH 2048

__device__ __forceinline__ void g2lds16(const void* g, void* l) {
  __builtin_amdgcn_global_load_lds((const __attribute__((address_space(1))) void*)g,
                                   (__attribute__((address_space(3))) void*)l, 16, 0, 0);
}

__device__ __forceinline__ short f2bf(float f) {
  union { __hip_bfloat16 h; unsigned short u; } c;
  c.h = __float2bfloat16(f);
  return (short)c.u;
}

// ---------------- gate + routing + gather ----------------
__global__ __launch_bounds__(256)
void gate_kernel(const float* __restrict__ x, const float* __restrict__ gate_w,
                 const float* __restrict__ bias,
                 __hip_bfloat16* __restrict__ xbf, __hip_bfloat16* __restrict__ Xg,
                 int* __restrict__ counts, int* __restrict__ assign_token,
                 float* __restrict__ assign_w) {
  const int wv = threadIdx.x >> 6, lane = threadIdx.x & 63;
  const int n = blockIdx.x * 4 + wv;
  const float4* xr = reinterpret_cast<const float4*>(x + (size_t)n * DDIM);
  float4 xv0 = xr[lane * 4 + 0], xv1 = xr[lane * 4 + 1];
  float4 xv2 = xr[lane * 4 + 2], xv3 = xr[lane * 4 + 3];

  float best = -1e30f, second = -1e30f; int bi = 0, si = 0;
  for (int e = 0; e < NEXP; e++) {
    const float4* gw = reinterpret_cast<const float4*>(gate_w + (size_t)e * DDIM);
    float4 g0 = gw[lane * 4 + 0], g1 = gw[lane * 4 + 1];
    float4 g2 = gw[lane * 4 + 2], g3 = gw[lane * 4 + 3];
    float s = g0.x*xv0.x + g0.y*xv0.y + g0.z*xv0.z + g0.w*xv0.w
            + g1.x*xv1.x + g1.y*xv1.y + g1.z*xv1.z + g1.w*xv1.w
            + g2.x*xv2.x + g2.y*xv2.y + g2.z*xv2.z + g2.w*xv2.w
            + g3.x*xv3.x + g3.y*xv3.y + g3.z*xv3.z + g3.w*xv3.w;
    #pragma unroll
    for (int off = 32; off > 0; off >>= 1) s += __shfl_xor(s, off);
    s = 1.f / (1.f + expf(-s)) + bias[e];
    if (s > best)        { second = best; si = bi; best = s; bi = e; }
    else if (s > second) { second = s; si = e; }
  }
  float denom = best + second + 1e-20f;
  float w0 = best / denom, w1 = second / denom;

  short8 p0, p1;
  p0[0]=f2bf(xv0.x); p0[1]=f2bf(xv0.y); p0[2]=f2bf(xv0.z); p0[3]=f2bf(xv0.w);
  p0[4]=f2bf(xv1.x); p0[5]=f2bf(xv1.y); p0[6]=f2bf(xv1.z); p0[7]=f2bf(xv1.w);
  p1[0]=f2bf(xv2.x); p1[1]=f2bf(xv2.y); p1[2]=f2bf(xv2.z); p1[3]=f2bf(xv2.w);
  p1[4]=f2bf(xv3.x); p1[5]=f2bf(xv3.y); p1[6]=f2bf(xv3.z); p1[7]=f2bf(xv3.w);

  short8* xo = (short8*)(xbf + (size_t)n * DDIM);
  xo[lane * 2] = p0; xo[lane * 2 + 1] = p1;

  int slot0 = -1, slot1 = -1;
  if (lane == 0) {
    int p = atomicAdd(&counts[bi], 1);
    if (p < CAP) slot0 = bi * CAP + p;
    p = atomicAdd(&counts[si], 1);
    if (p < CAP) slot1 = si * CAP + p;
  }
  slot0 = __shfl(slot0, 0); slot1 = __shfl(slot1, 0);
  if (slot0 >= 0) {
    if (lane == 0) { assign_token[slot0] = n; assign_w[slot0] = w0; }
    short8* o = (short8*)(Xg + (size_t)slot0 * DDIM);
    o[lane * 2] = p0; o[lane * 2 + 1] = p1;
  }
  if (slot1 >= 0) {
    if (lane == 0) { assign_token[slot1] = n; assign_w[slot1] = w1; }
    short8* o = (short8*)(Xg + (size_t)slot1 * DDIM);
    o[lane * 2] = p0; o[lane * 2 + 1] = p1;
  }
}

// ---------------- shared GEMM core ----------------
// C[BM x BN] tile = A(bf16, row-major, ld=lda) @ B(fp32, row-major, ld=ldB)
// liveM: only m-fragments with row_base < liveM are staged/computed (16-row gran).
// B staging spread over all 256 threads; B regs for step k+1 prefetched under MFMA.
__device__ __forceinline__ void gemm_core(
    const __hip_bfloat16* __restrict__ Ab, int lda,
    const float* __restrict__ Bb, int ldB,
    int k_begin, int k_end, int liveM,
    __hip_bfloat16* sA, unsigned char* sB, floatx4 (&acc)[4][8]) {
  const int tid = threadIdx.x;
  const int wv = tid >> 6, lane = tid & 63;
  const int rl = lane & 15, qd = lane >> 4;
  const int bn0 = (tid & 31) * 4;      // B stage: col base (4 cols)
  const int bkr = (tid >> 5) * 4;      // B stage: row base within BK (0..28)
  const int bq  = bkr >> 3;            // 16B unit within 8-k chunk
  const int bh  = (bkr >> 2) & 1;      // 8B half within unit

  float4 rr[4];
  {
    const float* bp = Bb + (size_t)(k_begin + bkr) * ldB + bn0;
    #pragma unroll
    for (int j = 0; j < 4; j++) rr[j] = *(const float4*)(bp + (size_t)j * ldB);
  }

  for (int k0 = k_begin; k0 < k_end; k0 += BK) {
    // -- stage A: live 16-row frags only, async global->LDS, 16B/lane --
    #pragma unroll
    for (int i = 0; i < 4; i++) {
      int rowbase = (i * 4 + wv) * 16;
      if (rowbase < liveM) {
        int c = (i * 4 + wv) * 64 + lane;
        int row = c >> 2, q = c & 3;
        g2lds16((const void*)(Ab + (size_t)row * lda + k0 + q * 8),
                (void*)(sA + (size_t)(i * 4 + wv) * 512));
      }
    }
    // -- stage B: regs (fp32) -> bf16, transposed into swizzled LDS [n][k] --
    #pragma unroll
    for (int jj = 0; jj < 4; jj++) {
      int n = bn0 + jj;
      short4v v;
      v[0] = f2bf(((const float*)&rr[0])[jj]);
      v[1] = f2bf(((const float*)&rr[1])[jj]);
      v[2] = f2bf(((const float*)&rr[2])[jj]);
      v[3] = f2bf(((const float*)&rr[3])[jj]);
      int qp = bq ^ (((n >> 2) + (n >> 4)) & 3);
      *(short4v*)(sB + (size_t)n * 80 + qp * 16 + bh * 8) = v;
    }
    __syncthreads();
    // -- prefetch next step's B into regs (hides HBM latency under MFMA) --
    if (k0 + BK < k_end) {
      const float* bp = Bb + (size_t)(k0 + BK + bkr) * ldB + bn0;
      #pragma unroll
      for (int j = 0; j < 4; j++) rr[j] = *(const float4*)(bp + (size_t)j * ldB);
    }
    // -- compute: only waves/frags with live rows --
    if (wv * 64 < liveM) {
      short8 bfr[8];
      #pragma unroll
      for (int ns = 0; ns < 8; ns++) {
        int n = ns * 16 + rl;
        int qp = qd ^ (((n >> 2) + (n >> 4)) & 3);
        bfr[ns] = *(const short8*)(sB + (size_t)n * 80 + qp * 16);
      }
      #pragma unroll
      for (int m = 0; m < 4; m++) {
        if (wv * 64 + m * 16 < liveM) {
          int row = wv * 64 + m * 16 + rl;
          short8 af = *(const short8*)((const unsigned char*)sA + (size_t)row * 64 + qd * 16);
          #pragma unroll
          for (int ns = 0; ns < 8; ns++)
            acc[m][ns] = __builtin_amdgcn_mfma_f32_16x16x32_bf16(af, bfr[ns], acc[m][ns], 0, 0, 0);
        }
      }
    }
    __syncthreads();
  }
}

// ---------------- FC1: experts (by<32) + shared (by>=32), silu -> bf16 ----------------
__global__ __launch_bounds__(256, 2)
void fc1_kernel(const __hip_bfloat16* __restrict__ xbf, const __hip_bfloat16* __restrict__ Xg,
                const float* __restrict__ sw1, const float* __restrict__ ew1,
                __hip_bfloat16* __restrict__ Hs, __hip_bfloat16* __restrict__ H,
                const int* __restrict__ counts) {
  __shared__ __align__(16) __hip_bfloat16 sA[BM * BK];
  __shared__ __align__(16) unsigned char sB[BN * 80];
  const int bx = blockIdx.x, by = blockIdx.y;
  const int tid = threadIdx.x, wv = tid >> 6, lane = tid & 63;
  const int rl = lane & 15, qd = lane >> 4;

  const __hip_bfloat16* Ab; const float* Bb; __hip_bfloat16* Co;
  int ldB, ldC, liveM;
  if (by < NEXP) {
    Ab = Xg + (size_t)by * CAP * DDIM;
    Bb = ew1 + (size_t)by * DDIM * HDIM + (size_t)bx * BN; ldB = HDIM;
    Co = H + (size_t)by * CAP * HDIM; ldC = HDIM;
    liveM = min(counts[by], CAP);
    if (liveM == 0) return;
  } else {
    if (bx >= HSH / BN) return;
    int mb = by - NEXP;
    Ab = xbf + (size_t)mb * BM * DDIM;
    Bb = sw1 + (size_t)bx * BN; ldB = HSH;
    Co = Hs + (size_t)mb * BM * HSH; ldC = HSH;
    liveM = BM;
  }

  floatx4 acc[4][8];
  #pragma unroll
  for (int m = 0; m < 4; m++)
    #pragma unroll
    for (int ns = 0; ns < 8; ns++) acc[m][ns] = (floatx4){0.f, 0.f, 0.f, 0.f};

  gemm_core(Ab, DDIM, Bb, ldB, 0, DDIM, liveM, sA, sB, acc);

  const int colbase = bx * BN;
  #pragma unroll
  for (int m = 0; m < 4; m++) {
    if (wv * 64 + m * 16 < liveM) {
      #pragma unroll
      for (int r = 0; r < 4; r++) {
        int row = wv * 64 + m * 16 + qd * 4 + r;
        #pragma unroll
        for (int ns = 0; ns < 8; ns++) {
          float v = acc[m][ns][r];
          float sv = v / (1.f + __expf(-v));   // silu
          Co[(size_t)row * ldC + colbase + ns * 16 + rl] = __float2bfloat16(sv);
        }
      }
    }
  }
}

// ---------------- FC2: experts (by<32, weighted scatter) + shared (by>=32) ----------------
__global__ __launch_bounds__(256, 2)
void fc2_kernel(const __hip_bfloat16* __restrict__ H, const __hip_bfloat16* __restrict__ Hs,
                const float* __restrict__ sw2, const float* __restrict__ ew2,
                float* __restrict__ out, const int* __restrict__ counts,
                const int* __restrict__ assign_token, const float* __restrict__ assign_w) {
  __shared__ __align__(16) __hip_bfloat16 sA[BM * BK];
  __shared__ __align__(16) unsigned char sB[BN * 80];
  const int bx = blockIdx.x, by = blockIdx.y, bz = blockIdx.z;
  const int tid = threadIdx.x, wv = tid >> 6, lane = tid & 63;
  const int rl = lane & 15, qd = lane >> 4;
  const bool isexp = (by < NEXP);

  const __hip_bfloat16* Ab; const float* Bb;
  int lda, kb, ke, liveM;
  if (isexp) {
    if (bz >= 2) return;                 // experts: split-K 2 over HDIM
    liveM = min(counts[by], CAP);
    if (liveM == 0) return;
    Ab = H + (size_t)by * CAP * HDIM; lda = HDIM;
    Bb = ew2 + (size_t)by * HDIM * DDIM + (size_t)bx * BN;
    kb = bz * (HDIM / 2); ke = kb + HDIM / 2;
  } else {
    int mb = by - NEXP;                  // shared: split-K 4 over HSH
    Ab = Hs + (size_t)mb * BM * HSH; lda = HSH;
    Bb = sw2 + (size_t)bx * BN;
    kb = bz * (HSH / 4); ke = kb + HSH / 4;
    liveM = BM;
  }

  floatx4 acc[4][8];
  #pragma unroll
  for (int m = 0; m < 4; m++)
    #pragma unroll
    for (int ns = 0; ns < 8; ns++) acc[m][ns] = (floatx4){0.f, 0.f, 0.f, 0.f};

  gemm_core(Ab, lda, Bb, DDIM, kb, ke, liveM, sA, sB, acc);

  const int colbase = bx * BN;
  if (isexp) {
    #pragma unroll
    for (int m = 0; m < 4; m++) {
      if (wv * 64 + m * 16 < liveM) {
        #pragma unroll
        for (int r = 0; r < 4; r++) {
          int row = wv * 64 + m * 16 + qd * 4 + r;
          int slot = by * CAP + row;
          int tok = assign_token[slot];
          if (tok >= 0) {
            float wgt = assign_w[slot];
            #pragma unroll
            for (int ns = 0; ns < 8; ns++)
              atomicAdd(out + (size_t)tok * DDIM + colbase + ns * 16 + rl, wgt * acc[m][ns][r]);
          }
        }
      }
    }
  } else {
    int mb = by - NEXP;
    #pragma unroll
    for (int m = 0; m < 4; m++) {
      #pragma unroll
      for (int r = 0; r < 4; r++) {
        int row = wv * 64 + m * 16 + qd * 4 + r;
        #pragma unroll
        for (int ns = 0; ns < 8; ns++)
          atomicAdd(out + ((size_t)mb * BM + row) * DDIM + colbase + ns * 16 + rl, acc[m][ns][r]);
      }
    }
  }
}

// ---------------- launch ----------------
extern "C" void kernel_launch(void* const* d_in, const int* in_sizes, int n_in,
                              void* d_out, int out_size, void* d_ws, size_t ws_size,
                              hipStream_t stream) {
  const float* x         = (const float*)d_in[0];
  const float* gate_w    = (const float*)d_in[1];
  const float* bias      = (const float*)d_in[2];
  const float* shared_w1 = (const float*)d_in[3];
  const float* shared_w2 = (const float*)d_in[4];
  const float* expert_w1 = (const float*)d_in[5];
  const float* expert_w2 = (const float*)d_in[6];
  float* out = (float*)d_out;

  char* w = (char*)d_ws;
  int*   counts       = (int*)w;                      // 32 ints
  int*   assign_token = (int*)(w + 256);              // 8192 ints
  float* assign_w     = (float*)(w + 256 + 32768);    // 8192 floats
  size_t off = 256 + 32768 + 32768;
  __hip_bfloat16* xbf = (__hip_bfloat16*)(w + off); off += (size_t)NTOK * DDIM * 2;       // 4 MB
  __hip_bfloat16* Xg  = (__hip_bfloat16*)(w + off); off += (size_t)NEXP * CAP * DDIM * 2; // 16 MB
  __hip_bfloat16* Hs  = (__hip_bfloat16*)(w + off); off += (size_t)NTOK * HSH * 2;        // 8 MB
  __hip_bfloat16* H   = (__hip_bfloat16*)(w + off); off += (size_t)NEXP * CAP * HDIM * 2; // 64 MB

  hipMemsetAsync(counts, 0, 256, stream);
  hipMemsetAsync(assign_token, 0xFF, 32768, stream);          // -1 sentinel
  hipMemsetAsync(d_out, 0, (size_t)out_size * 4, stream);     // split-K accumulates

  gate_kernel<<<NTOK / 4, 256, 0, stream>>>(x, gate_w, bias, xbf, Xg,
                                            counts, assign_token, assign_w);

  // FC1 merged: experts (by 0..31, bx<32) + shared (by 32..39, bx<16)
  fc1_kernel<<<dim3(HDIM / BN, NEXP + NTOK / BM), 256, 0, stream>>>(
      xbf, Xg, shared_w1, expert_w1, Hs, H, counts);

  // FC2 merged: experts (by 0..31, z<2) + shared (by 32..39, z<4)
  fc2_kernel<<<dim3(DDIM / BN, NEXP + NTOK / BM, 4), 256, 0, stream>>>(
      H, Hs, shared_w2, expert_w2, out, counts, assign_token, assign_w);
}

// Round 2
// 1159.705 us; speedup vs baseline: 1.1384x; 1.0134x over previous
//
#include <hip/hip_runtime.h>
#include <hip/hip_bf16.h>

typedef __attribute__((ext_vector_type(8))) short short8;
typedef __attribute__((ext_vector_type(4))) float floatx4;

#define BM 256
#define BN 128
#define BK 64
#define CAP 256      // max tokens per expert (mean 128, sigma ~11 -> safe)
#define NEXP 32
#define NTOK 2048
#define DDIM 1024
#define HDIM 4096
#define HSH 2048

__device__ __forceinline__ void g2lds16(const void* g, void* l) {
  __builtin_amdgcn_global_load_lds((const __attribute__((address_space(1))) void*)g,
                                   (__attribute__((address_space(3))) void*)l, 16, 0, 0);
}

__device__ __forceinline__ short f2bf(float f) {
  union { __hip_bfloat16 h; unsigned short u; } c;
  c.h = __float2bfloat16(f);
  return (short)c.u;
}

// ---------------- gate + routing + gather ----------------
__global__ __launch_bounds__(256)
void gate_kernel(const float* __restrict__ x, const float* __restrict__ gate_w,
                 const float* __restrict__ bias,
                 __hip_bfloat16* __restrict__ xbf, __hip_bfloat16* __restrict__ Xg,
                 int* __restrict__ counts, int* __restrict__ assign_token,
                 float* __restrict__ assign_w) {
  const int wv = threadIdx.x >> 6, lane = threadIdx.x & 63;
  const int n = blockIdx.x * 4 + wv;
  const float4* xr = reinterpret_cast<const float4*>(x + (size_t)n * DDIM);
  float4 xv0 = xr[lane * 4 + 0], xv1 = xr[lane * 4 + 1];
  float4 xv2 = xr[lane * 4 + 2], xv3 = xr[lane * 4 + 3];

  float best = -1e30f, second = -1e30f; int bi = 0, si = 0;
  for (int e = 0; e < NEXP; e++) {
    const float4* gw = reinterpret_cast<const float4*>(gate_w + (size_t)e * DDIM);
    float4 g0 = gw[lane * 4 + 0], g1 = gw[lane * 4 + 1];
    float4 g2 = gw[lane * 4 + 2], g3 = gw[lane * 4 + 3];
    float s = g0.x*xv0.x + g0.y*xv0.y + g0.z*xv0.z + g0.w*xv0.w
            + g1.x*xv1.x + g1.y*xv1.y + g1.z*xv1.z + g1.w*xv1.w
            + g2.x*xv2.x + g2.y*xv2.y + g2.z*xv2.z + g2.w*xv2.w
            + g3.x*xv3.x + g3.y*xv3.y + g3.z*xv3.z + g3.w*xv3.w;
    #pragma unroll
    for (int off = 32; off > 0; off >>= 1) s += __shfl_xor(s, off);
    s = 1.f / (1.f + expf(-s)) + bias[e];
    if (s > best)        { second = best; si = bi; best = s; bi = e; }
    else if (s > second) { second = s; si = e; }
  }
  float denom = best + second + 1e-20f;
  float w0 = best / denom, w1 = second / denom;

  short8 p0, p1;
  p0[0]=f2bf(xv0.x); p0[1]=f2bf(xv0.y); p0[2]=f2bf(xv0.z); p0[3]=f2bf(xv0.w);
  p0[4]=f2bf(xv1.x); p0[5]=f2bf(xv1.y); p0[6]=f2bf(xv1.z); p0[7]=f2bf(xv1.w);
  p1[0]=f2bf(xv2.x); p1[1]=f2bf(xv2.y); p1[2]=f2bf(xv2.z); p1[3]=f2bf(xv2.w);
  p1[4]=f2bf(xv3.x); p1[5]=f2bf(xv3.y); p1[6]=f2bf(xv3.z); p1[7]=f2bf(xv3.w);

  short8* xo = (short8*)(xbf + (size_t)n * DDIM);
  xo[lane * 2] = p0; xo[lane * 2 + 1] = p1;

  int slot0 = -1, slot1 = -1;
  if (lane == 0) {
    int p = atomicAdd(&counts[bi], 1);
    if (p < CAP) slot0 = bi * CAP + p;
    p = atomicAdd(&counts[si], 1);
    if (p < CAP) slot1 = si * CAP + p;
  }
  slot0 = __shfl(slot0, 0); slot1 = __shfl(slot1, 0);
  if (slot0 >= 0) {
    if (lane == 0) { assign_token[slot0] = n; assign_w[slot0] = w0; }
    short8* o = (short8*)(Xg + (size_t)slot0 * DDIM);
    o[lane * 2] = p0; o[lane * 2 + 1] = p1;
  }
  if (slot1 >= 0) {
    if (lane == 0) { assign_token[slot1] = n; assign_w[slot1] = w1; }
    short8* o = (short8*)(Xg + (size_t)slot1 * DDIM);
    o[lane * 2] = p0; o[lane * 2 + 1] = p1;
  }
}

// ---------------- shared GEMM core (BK=64) ----------------
// C[BM x BN] tile = A(bf16, row-major, ld=lda) @ B(fp32, row-major, ld=ldB)
// A: global->LDS async, source pre-swizzled (u ^= row&7) so frag reads are
//    bank-quad-uniform on the linear LDS dest (rule 21: both-sides-or-neither).
// B: reg-staged fp32->bf16, [n][k-units] with qp = u ^ (((n>>2)+(n>>4))&7),
//    row stride 144B -> uniform 8 lanes/quad on both ds_write and ds_read.
// liveM: A staged at 8-row gran, MFMA/epilogue at 16-row gran.
__device__ __forceinline__ void gemm_core(
    const __hip_bfloat16* __restrict__ Ab, int lda,
    const float* __restrict__ Bb, int ldB,
    int k_begin, int k_end, int liveM,
    __hip_bfloat16* sA, unsigned char* sB, floatx4 (&acc)[4][8]) {
  const int tid = threadIdx.x;
  const int wv = tid >> 6, lane = tid & 63;
  const int rl = lane & 15, qd = lane >> 4;
  const int bn0 = (tid & 31) * 4;   // B stage: col base (4 cols)
  const int bu  = tid >> 5;         // B stage: k-unit 0..7 (8 k-rows each)
  const int bkr = bu * 8;

  float4 rr[8];
  {
    const float* bp = Bb + (size_t)(k_begin + bkr) * ldB + bn0;
    #pragma unroll
    for (int j = 0; j < 8; j++) rr[j] = *(const float4*)(bp + (size_t)j * ldB);
  }

  for (int k0 = k_begin; k0 < k_end; k0 += BK) {
    // -- stage A: 256x64 bf16, 8 wave-uniform 1KB issues, pre-swizzled source --
    #pragma unroll
    for (int i = 0; i < 8; i++) {
      int grp = i * 4 + wv;
      if (grp * 8 < liveM) {
        int c = grp * 64 + lane;          // 16B-chunk id
        int row = c >> 3;
        int u = (c & 7) ^ (row & 7);      // inverse swizzle on source
        g2lds16((const void*)(Ab + (size_t)row * lda + k0 + u * 8),
                (void*)(sA + (size_t)grp * 512));
      }
    }
    // -- stage B: regs (fp32) -> bf16, swizzled LDS [n][k] --
    #pragma unroll
    for (int jj = 0; jj < 4; jj++) {
      int n = bn0 + jj;
      short8 v;
      #pragma unroll
      for (int i = 0; i < 8; i++) v[i] = f2bf(((const float*)&rr[i])[jj]);
      int qp = bu ^ (((n >> 2) + (n >> 4)) & 7);
      *(short8*)(sB + (size_t)n * 144 + qp * 16) = v;
    }
    __syncthreads();
    // -- prefetch next step's B into regs (hides HBM latency under MFMA) --
    if (k0 + BK < k_end) {
      const float* bp = Bb + (size_t)(k0 + BK + bkr) * ldB + bn0;
      #pragma unroll
      for (int j = 0; j < 8; j++) rr[j] = *(const float4*)(bp + (size_t)j * ldB);
    }
    // -- compute: 2 k-halves x 32 MFMA, live frags only --
    if (wv * 64 < liveM) {
      #pragma unroll
      for (int kk = 0; kk < 2; kk++) {
        short8 bfr[8];
        #pragma unroll
        for (int ns = 0; ns < 8; ns++) {
          int n = ns * 16 + rl;
          int qp = (kk * 4 + qd) ^ (((n >> 2) + (n >> 4)) & 7);
          bfr[ns] = *(const short8*)(sB + (size_t)n * 144 + qp * 16);
        }
        #pragma unroll
        for (int m = 0; m < 4; m++) {
          if (wv * 64 + m * 16 < liveM) {
            int row = wv * 64 + m * 16 + rl;
            int u = (kk * 4 + qd) ^ (rl & 7);
            short8 af = *(const short8*)((const unsigned char*)sA + (size_t)row * 128 + u * 16);
            #pragma unroll
            for (int ns = 0; ns < 8; ns++)
              acc[m][ns] = __builtin_amdgcn_mfma_f32_16x16x32_bf16(af, bfr[ns], acc[m][ns], 0, 0, 0);
          }
        }
      }
    }
    __syncthreads();
  }
}

// ---------------- FC1: experts (by<32) + shared (by>=32), silu -> bf16 ----------------
__global__ __launch_bounds__(256, 2)
void fc1_kernel(const __hip_bfloat16* __restrict__ xbf, const __hip_bfloat16* __restrict__ Xg,
                const float* __restrict__ sw1, const float* __restrict__ ew1,
                __hip_bfloat16* __restrict__ Hs, __hip_bfloat16* __restrict__ H,
                const int* __restrict__ counts) {
  __shared__ __align__(16) __hip_bfloat16 sA[BM * BK];
  __shared__ __align__(16) unsigned char sB[BN * 144];
  const int bx = blockIdx.x, by = blockIdx.y;
  const int tid = threadIdx.x, wv = tid >> 6, lane = tid & 63;
  const int rl = lane & 15, qd = lane >> 4;

  const __hip_bfloat16* Ab; const float* Bb; __hip_bfloat16* Co;
  int ldB, ldC, liveM;
  if (by < NEXP) {
    Ab = Xg + (size_t)by * CAP * DDIM;
    Bb = ew1 + (size_t)by * DDIM * HDIM + (size_t)bx * BN; ldB = HDIM;
    Co = H + (size_t)by * CAP * HDIM; ldC = HDIM;
    liveM = min(counts[by], CAP);
    if (liveM == 0) return;
  } else {
    if (bx >= HSH / BN) return;
    int mb = by - NEXP;
    Ab = xbf + (size_t)mb * BM * DDIM;
    Bb = sw1 + (size_t)bx * BN; ldB = HSH;
    Co = Hs + (size_t)mb * BM * HSH; ldC = HSH;
    liveM = BM;
  }

  floatx4 acc[4][8];
  #pragma unroll
  for (int m = 0; m < 4; m++)
    #pragma unroll
    for (int ns = 0; ns < 8; ns++) acc[m][ns] = (floatx4){0.f, 0.f, 0.f, 0.f};

  gemm_core(Ab, DDIM, Bb, ldB, 0, DDIM, liveM, sA, sB, acc);

  const int colbase = bx * BN;
  #pragma unroll
  for (int m = 0; m < 4; m++) {
    if (wv * 64 + m * 16 < liveM) {
      #pragma unroll
      for (int r = 0; r < 4; r++) {
        int row = wv * 64 + m * 16 + qd * 4 + r;
        #pragma unroll
        for (int ns = 0; ns < 8; ns++) {
          float v = acc[m][ns][r];
          float sv = v / (1.f + __expf(-v));   // silu
          Co[(size_t)row * ldC + colbase + ns * 16 + rl] = __float2bfloat16(sv);
        }
      }
    }
  }
}

// ---------------- FC2: experts (by<32, weighted scatter) + shared (by>=32) ----------------
__global__ __launch_bounds__(256, 2)
void fc2_kernel(const __hip_bfloat16* __restrict__ H, const __hip_bfloat16* __restrict__ Hs,
                const float* __restrict__ sw2, const float* __restrict__ ew2,
                float* __restrict__ out, const int* __restrict__ counts,
                const int* __restrict__ assign_token, const float* __restrict__ assign_w) {
  __shared__ __align__(16) __hip_bfloat16 sA[BM * BK];
  __shared__ __align__(16) unsigned char sB[BN * 144];
  const int bx = blockIdx.x, by = blockIdx.y, bz = blockIdx.z;
  const int tid = threadIdx.x, wv = tid >> 6, lane = tid & 63;
  const int rl = lane & 15, qd = lane >> 4;
  const bool isexp = (by < NEXP);

  const __hip_bfloat16* Ab; const float* Bb;
  int lda, kb, ke, liveM;
  if (isexp) {
    if (bz >= 2) return;                 // experts: split-K 2 over HDIM
    liveM = min(counts[by], CAP);
    if (liveM == 0) return;
    Ab = H + (size_t)by * CAP * HDIM; lda = HDIM;
    Bb = ew2 + (size_t)by * HDIM * DDIM + (size_t)bx * BN;
    kb = bz * (HDIM / 2); ke = kb + HDIM / 2;
  } else {
    int mb = by - NEXP;                  // shared: split-K 4 over HSH
    Ab = Hs + (size_t)mb * BM * HSH; lda = HSH;
    Bb = sw2 + (size_t)bx * BN;
    kb = bz * (HSH / 4); ke = kb + HSH / 4;
    liveM = BM;
  }

  floatx4 acc[4][8];
  #pragma unroll
  for (int m = 0; m < 4; m++)
    #pragma unroll
    for (int ns = 0; ns < 8; ns++) acc[m][ns] = (floatx4){0.f, 0.f, 0.f, 0.f};

  gemm_core(Ab, lda, Bb, DDIM, kb, ke, liveM, sA, sB, acc);

  const int colbase = bx * BN;
  if (isexp) {
    #pragma unroll
    for (int m = 0; m < 4; m++) {
      if (wv * 64 + m * 16 < liveM) {
        #pragma unroll
        for (int r = 0; r < 4; r++) {
          int row = wv * 64 + m * 16 + qd * 4 + r;
          int slot = by * CAP + row;
          int tok = assign_token[slot];
          if (tok >= 0) {
            float wgt = assign_w[slot];
            #pragma unroll
            for (int ns = 0; ns < 8; ns++)
              atomicAdd(out + (size_t)tok * DDIM + colbase + ns * 16 + rl, wgt * acc[m][ns][r]);
          }
        }
      }
    }
  } else {
    int mb = by - NEXP;
    #pragma unroll
    for (int m = 0; m < 4; m++) {
      #pragma unroll
      for (int r = 0; r < 4; r++) {
        int row = wv * 64 + m * 16 + qd * 4 + r;
        #pragma unroll
        for (int ns = 0; ns < 8; ns++)
          atomicAdd(out + ((size_t)mb * BM + row) * DDIM + colbase + ns * 16 + rl, acc[m][ns][r]);
      }
    }
  }
}

// ---------------- launch ----------------
extern "C" void kernel_launch(void* const* d_in, const int* in_sizes, int n_in,
                              void* d_out, int out_size, void* d_ws, size_t ws_size,
                              hipStream_t stream) {
  const float* x         = (const float*)d_in[0];
  const float* gate_w    = (const float*)d_in[1];
  const float* bias      = (const float*)d_in[2];
  const float* shared_w1 = (const float*)d_in[3];
  const float* shared_w2 = (const float*)d_in[4];
  const float* expert_w1 = (const float*)d_in[5];
  const float* expert_w2 = (const float*)d_in[6];
  float* out = (float*)d_out;

  char* w = (char*)d_ws;
  int*   counts       = (int*)w;                      // 32 ints
  int*   assign_token = (int*)(w + 256);              // 8192 ints
  float* assign_w     = (float*)(w + 256 + 32768);    // 8192 floats
  size_t off = 256 + 32768 + 32768;
  __hip_bfloat16* xbf = (__hip_bfloat16*)(w + off); off += (size_t)NTOK * DDIM * 2;       // 4 MB
  __hip_bfloat16* Xg  = (__hip_bfloat16*)(w + off); off += (size_t)NEXP * CAP * DDIM * 2; // 16 MB
  __hip_bfloat16* Hs  = (__hip_bfloat16*)(w + off); off += (size_t)NTOK * HSH * 2;        // 8 MB
  __hip_bfloat16* H   = (__hip_bfloat16*)(w + off); off += (size_t)NEXP * CAP * HDIM * 2; // 64 MB

  hipMemsetAsync(counts, 0, 256, stream);
  hipMemsetAsync(assign_token, 0xFF, 32768, stream);          // -1 sentinel
  hipMemsetAsync(d_out, 0, (size_t)out_size * 4, stream);     // split-K accumulates

  gate_kernel<<<NTOK / 4, 256, 0, stream>>>(x, gate_w, bias, xbf, Xg,
                                            counts, assign_token, assign_w);

  // FC1 merged: experts (by 0..31, bx<32) + shared (by 32..39, bx<16)
  fc1_kernel<<<dim3(HDIM / BN, NEXP + NTOK / BM), 256, 0, stream>>>(
      xbf, Xg, shared_w1, expert_w1, Hs, H, counts);

  // FC2 merged: experts (by 0..31, z<2) + shared (by 32..39, z<4)
  fc2_kernel<<<dim3(DDIM / BN, NEXP + NTOK / BM, 4), 256, 0, stream>>>(
      H, Hs, shared_w2, expert_w2, out, counts, assign_token, assign_w);
}